// Round 4
// baseline (334.706 us; speedup 1.0000x reference)
//
#include <hip/hip_runtime.h>

// Deformable 2x bilinear upsample — v4: barrier-cost reduction.
// input:  (B=8, C=128, H=128, W=128) fp32
// offset_x/offset_y: (B, 1, Ho=256, Wo=256) fp32
// out:    (B, C, Ho, Wo) fp32
//
// v0: scattered gathers, VMEM request-rate bound (218 us).
// v2: LDS-staged, TCC-traffic bound (311 us, 8x staging amp + write amp).
// v3: 1024-thr / 16-row tiles / XCD remap / NT stores (~155 us).
// v4: __syncthreads drains vmcnt(0) incl. NT-store acks -> 32 full store
//     drains per block. Replace with LDS-only barriers (lgkmcnt(0) +
//     raw s_barrier), single barrier per stage, NC=4 (8 stages).

constexpr int B  = 8;
constexpr int C  = 128;
constexpr int H  = 128;
constexpr int W  = 128;
constexpr int KH = 2;
constexpr int KW = 2;
constexpr int Ho = H * KH;     // 256
constexpr int Wo = W * KW;     // 256
constexpr int HW = H * W;      // 16384
constexpr int CG  = 4;         // channel groups
constexpr int CPG = C / CG;    // 32 channels per block
constexpr int NC  = 4;         // channels staged per stage
constexpr int NSTAGE = CPG / NC;   // 8
constexpr int TR = 16;         // output rows per block
constexpr int ADV = TR / 2;    // 8 input rows advanced per x-tile
constexpr int WR = 16;         // staged window rows
constexpr int WWORDS = WR * W; // 2048 words per channel window
constexpr int PACK = NC * WWORDS;  // 8192 words per stage
constexpr int NXT = Ho / TR;   // 16 x-tiles

using f32x4 = __attribute__((ext_vector_type(4))) float;

// LDS-only barrier: orders ds_write->ds_read across the workgroup WITHOUT
// draining outstanding VMEM (nontemporal stores keep flying).
__device__ inline void lds_barrier() {
    asm volatile("s_waitcnt lgkmcnt(0)" ::: "memory");
    __builtin_amdgcn_s_barrier();
}

__global__ __launch_bounds__(1024, 8) void deform_upsample_kernel(
    const float* __restrict__ in,
    const float* __restrict__ offx,
    const float* __restrict__ offy,
    float* __restrict__ out)
{
    __shared__ float smem[2][PACK];   // 2 x 32 KiB (double buffer)

    // XCD-chunked remap (HW round-robins wgid%8 across XCDs): XCD x owns
    // slices (b,cg) in [4x,4x+4); bx walks overlapping row-tiles -> local L2.
    const int wgid  = blockIdx.x;            // 0..511
    const int xcd   = wgid & 7;
    const int k     = wgid >> 3;             // 0..63
    const int bx    = k & (NXT - 1);         // 0..15
    const int slice = xcd * 4 + (k >> 4);    // 0..31
    const int bz    = slice & (CG - 1);
    const int b     = slice >> 2;

    const int t    = threadIdx.x;
    const int lane = t & 63;
    const int wv   = t >> 6;                 // wave 0..15, one output row each
    const int wo4  = lane * 4;
    const int ho   = bx * TR + wv;
    const int c0   = bz * CPG;

    const int iy0 = min(max(bx * ADV - 4, 0), H - WR);   // window start

    // ---- staging: thread t covers two float4 segments of the 8192-word pack
    const int fw0 = t * 4;           // channels 0..1 of the stage
    const int fw1 = t * 4 + 4096;    // channels 2..3 of the stage
    const float* gsrcA = in + (size_t)(b * C + c0 + (fw0 >> 11)) * HW
                            + iy0 * W + (fw0 & (WWORDS - 1));
    const float* gsrcB = in + (size_t)(b * C + c0 + (fw1 >> 11)) * HW
                            + iy0 * W + (fw1 & (WWORDS - 1));

    // stage-0 loads issued ASAP (latency overlaps coordinate math)
    float4 stgA = *reinterpret_cast<const float4*>(gsrcA);
    float4 stgB = *reinterpret_cast<const float4*>(gsrcB);

    // ---- per-position coordinate precompute (channel-invariant) ----
    const int sbase = (b * Ho + ho) * Wo + wo4;
    const float4 ox4 = *reinterpret_cast<const float4*>(offx + sbase);
    const float4 oy4 = *reinterpret_cast<const float4*>(offy + sbase);
    const float oxv[4] = {ox4.x, ox4.y, ox4.z, ox4.w};
    const float oyv[4] = {oy4.x, oy4.y, oy4.z, oy4.w};

    float wt0[4], wt1[4], wb0[4], wb1[4];  // (top,bot) x (word0,word1) weights
    int   otv[4], obv[4];                  // LDS word offsets of top/bot pairs
    unsigned fbmask = 0;                   // positions needing global fallback

    const float base_y = (float)ho * 0.5f;
#pragma unroll
    for (int j = 0; j < 4; ++j) {
        const float y = base_y + oyv[j];
        const float x = (float)(wo4 + j) * 0.5f + oxv[j];
        const float y0f = floorf(y), x0f = floorf(x);
        const float wy = y - y0f, wx = x - x0f;
        const int y0 = (int)y0f, x0 = (int)x0f;
        const int y1 = y0 + 1, x1 = x0 + 1;
        const bool vy0 = ((unsigned)y0 < (unsigned)H);
        const bool vy1 = ((unsigned)y1 < (unsigned)H);
        const bool vx0 = ((unsigned)x0 < (unsigned)W);
        const bool vx1 = ((unsigned)x1 < (unsigned)W);
        const int yc0 = min(max(y0, 0), H - 1);
        const int yc1 = min(max(y1, 0), H - 1);
        const int xc0 = min(max(x0, 0), W - 1);
        const int xc1 = min(max(x1, 0), W - 1);
        const int xb  = min(max(x0, 0), W - 2);   // pair base; xc0,xc1 in {xb,xb+1}

        const float omwy = 1.0f - wy, omwx = 1.0f - wx;
        const float w00 = (vy0 && vx0) ? (omwy * omwx) : 0.0f;
        const float w01 = (vy0 && vx1) ? (omwy * wx)   : 0.0f;
        const float w10 = (vy1 && vx0) ? (wy * omwx)   : 0.0f;
        const float w11 = (vy1 && vx1) ? (wy * wx)     : 0.0f;

        // fold x-clamp into pair weights: corner value = word0 if xc==xb else word1
        wt0[j] = (xc0 == xb ? w00 : 0.0f) + (xc1 == xb ? w01 : 0.0f);
        wt1[j] = (xc0 == xb ? 0.0f : w00) + (xc1 == xb ? 0.0f : w01);
        wb0[j] = (xc0 == xb ? w10 : 0.0f) + (xc1 == xb ? w11 : 0.0f);
        wb1[j] = (xc0 == xb ? 0.0f : w10) + (xc1 == xb ? 0.0f : w11);

        const int yr0 = yc0 - iy0, yr1 = yc1 - iy0;
        fbmask |= (unsigned)((yr0 < 0) | (yr1 > WR - 1)) << j;
        const int yr0c = min(max(yr0, 0), WR - 1);
        const int yr1c = min(max(yr1, 0), WR - 1);
        otv[j] = yr0c * W + xb;
        obv[j] = yr1c * W + xb;
    }

    // prologue: publish stage 0, put stage 1 in flight
    *reinterpret_cast<float4*>(&smem[0][fw0]) = stgA;
    *reinterpret_cast<float4*>(&smem[0][fw1]) = stgB;
    gsrcA += NC * HW;  gsrcB += NC * HW;
    stgA = *reinterpret_cast<const float4*>(gsrcA);
    stgB = *reinterpret_cast<const float4*>(gsrcB);
    lds_barrier();

    const float* ipfb = in + (size_t)(b * C + c0) * HW;
    float* op = out + ((size_t)(b * C + c0) * Ho + ho) * Wo + wo4;

    for (int s = 0; s < NSTAGE; ++s) {
        const int cur = s & 1;

        // publish stage s+1 into the other buffer (nobody reads it this phase;
        // its previous readers finished before the last barrier)
        if (s + 1 < NSTAGE) {
            *reinterpret_cast<float4*>(&smem[cur ^ 1][fw0]) = stgA;
            *reinterpret_cast<float4*>(&smem[cur ^ 1][fw1]) = stgB;
            if (s + 2 < NSTAGE) {
                gsrcA += NC * HW;  gsrcB += NC * HW;
                stgA = *reinterpret_cast<const float4*>(gsrcA);   // s+2 in flight
                stgB = *reinterpret_cast<const float4*>(gsrcB);
            }
        }

#pragma unroll
        for (int c = 0; c < NC; ++c) {
            const float* lw = &smem[cur][c * WWORDS];
            float r[4];
#pragma unroll
            for (int j = 0; j < 4; ++j) {
                const float t0v = lw[otv[j]];
                const float t1v = lw[otv[j] + 1];   // merges to ds_read2_b32
                const float b0v = lw[obv[j]];
                const float b1v = lw[obv[j] + 1];
                float acc = wt0[j] * t0v;
                acc = fmaf(wt1[j], t1v, acc);
                acc = fmaf(wb0[j], b0v, acc);
                acc = fmaf(wb1[j], b1v, acc);
                r[j] = acc;
            }
            if (__builtin_expect(fbmask != 0u, 0)) {   // ~2e-4/position
                const float* ipc = ipfb + (size_t)(s * NC + c) * HW;
#pragma unroll
                for (int j = 0; j < 4; ++j) {
                    if ((fbmask >> j) & 1u) {
                        const float oyj = offy[sbase + j];     // cold reload
                        const float y = base_y + oyj;
                        const int y0 = (int)floorf(y);
                        const int yc0 = min(max(y0, 0), H - 1);
                        const int yc1 = min(max(y0 + 1, 0), H - 1);
                        const int xb  = otv[j] & (W - 1);
                        const float t0v = ipc[yc0 * W + xb];
                        const float t1v = ipc[yc0 * W + xb + 1];
                        const float b0v = ipc[yc1 * W + xb];
                        const float b1v = ipc[yc1 * W + xb + 1];
                        float acc = wt0[j] * t0v;
                        acc = fmaf(wt1[j], t1v, acc);
                        acc = fmaf(wb0[j], b0v, acc);
                        acc = fmaf(wb1[j], b1v, acc);
                        r[j] = acc;
                    }
                }
            }
            // streaming store: output never re-read; keep it out of L2.
            // NOT drained at barriers (lds_barrier waits lgkmcnt only).
            f32x4 rv = {r[0], r[1], r[2], r[3]};
            __builtin_nontemporal_store(
                rv, reinterpret_cast<f32x4*>(op + (size_t)(s * NC + c) * (size_t)(Ho * Wo)));
        }

        if (s + 1 < NSTAGE)
            lds_barrier();   // stage s+1 visible; stage-s reads complete
    }
}

extern "C" void kernel_launch(void* const* d_in, const int* in_sizes, int n_in,
                              void* d_out, int out_size, void* d_ws, size_t ws_size,
                              hipStream_t stream) {
    const float* in   = (const float*)d_in[0];
    const float* offx = (const float*)d_in[1];
    const float* offy = (const float*)d_in[2];
    float* out = (float*)d_out;

    dim3 grid(NXT * B * CG);   // 512 blocks = 2 blocks/CU (1024 thr each)
    dim3 block(1024);
    deform_upsample_kernel<<<grid, block, 0, stream>>>(in, offx, offy, out);
}